// Round 1
// baseline (278.170 us; speedup 1.0000x reference)
//
#include <hip/hip_runtime.h>
#include <math.h>

// Problem constants
#define B_   128
#define K_   4
#define HW_  65536              // 256*256

constexpr int BLOCK  = 256;
constexpr int CHUNK  = 4096;            // floats of HW per block
constexpr int NCHUNK = HW_ / CHUNK;     // 16 chunks per b
constexpr int V4_PER_THREAD = CHUNK / 4 / BLOCK; // 4 float4 per thread per tensor

// Per-element math: given x (logit) and t (0/1 target), accumulate
//   fs  += ALPHA * (1 - exp(-bce))^2 * bce    with bce = max(x,0) - x*t + log1p(e^{-|x|})
//   ps  += clip(sigmoid(x), 1e-4, 1-1e-4)
//   in  += clip_sig * t
//   ms  += (x >= 0)
//   i2  += (x >= 0) * t
// Note exp(-bce) == t*s + (1-t)*(1-s) analytically (s = sigmoid(x)) — saves one expf.
__device__ __forceinline__ void proc_elem(float x, float t,
                                          float& fs, float& in, float& ps,
                                          float& i2, float& ms) {
    float ax  = fabsf(x);
    float e   = expf(-ax);
    float inv = 1.0f / (1.0f + e);
    bool  pos = (x >= 0.0f);
    float s   = pos ? inv : e * inv;          // sigmoid(x)
    float bce = fmaxf(x, 0.0f) - x * t + log1pf(e);
    float pt  = t * s + (1.0f - t) * (1.0f - s);   // == exp(-bce)
    float om  = 1.0f - pt;
    fs += 0.8f * om * om * bce;               // ALPHA = 0.8, GAMMA = 2
    float pc = fminf(fmaxf(s, 1e-4f), 1.0f - 1e-4f);
    ps += pc;
    in += pc * t;
    float m = pos ? 1.0f : 0.0f;
    ms += m;
    i2 += m * t;
}

__global__ __launch_bounds__(BLOCK) void partial_kernel(
    const float* __restrict__ pred_masks,   // B*K*HW
    const float* __restrict__ targets,      // B*HW
    float* __restrict__ fsum,               // B*K
    float* __restrict__ inter,              // B*K
    float* __restrict__ psum,               // B*K
    float* __restrict__ i2s,                // B*K
    float* __restrict__ msum,               // B*K
    float* __restrict__ tsum)               // B
{
    const int blk  = blockIdx.x;
    const int b    = blk / NCHUNK;
    const int c    = blk % NCHUNK;
    const int base = c * CHUNK;

    const float4* __restrict__ t4 =
        reinterpret_cast<const float4*>(targets + (size_t)b * HW_ + base);
    const float* __restrict__ xbase = pred_masks + (size_t)b * K_ * HW_ + base;

    float fs[K_] = {0.f, 0.f, 0.f, 0.f};
    float in[K_] = {0.f, 0.f, 0.f, 0.f};
    float ps[K_] = {0.f, 0.f, 0.f, 0.f};
    float i2[K_] = {0.f, 0.f, 0.f, 0.f};
    float ms[K_] = {0.f, 0.f, 0.f, 0.f};
    float ts = 0.f;

    #pragma unroll
    for (int i = 0; i < V4_PER_THREAD; ++i) {
        const int idx = threadIdx.x + i * BLOCK;   // float4 index within chunk
        const float4 tv = t4[idx];
        ts += tv.x + tv.y + tv.z + tv.w;
        #pragma unroll
        for (int k = 0; k < K_; ++k) {
            const float4 xv =
                reinterpret_cast<const float4*>(xbase + (size_t)k * HW_)[idx];
            proc_elem(xv.x, tv.x, fs[k], in[k], ps[k], i2[k], ms[k]);
            proc_elem(xv.y, tv.y, fs[k], in[k], ps[k], i2[k], ms[k]);
            proc_elem(xv.z, tv.z, fs[k], in[k], ps[k], i2[k], ms[k]);
            proc_elem(xv.w, tv.w, fs[k], in[k], ps[k], i2[k], ms[k]);
        }
    }

    // Pack 21 partials, wave-shuffle reduce (wave = 64), combine 4 waves via LDS.
    float vals[21];
    #pragma unroll
    for (int k = 0; k < K_; ++k) {
        vals[k]      = fs[k];
        vals[4 + k]  = in[k];
        vals[8 + k]  = ps[k];
        vals[12 + k] = i2[k];
        vals[16 + k] = ms[k];
    }
    vals[20] = ts;

    const int lane = threadIdx.x & 63;
    const int wave = threadIdx.x >> 6;

    #pragma unroll
    for (int v = 0; v < 21; ++v) {
        float x = vals[v];
        #pragma unroll
        for (int off = 32; off > 0; off >>= 1) x += __shfl_down(x, off, 64);
        vals[v] = x;
    }

    __shared__ float smem[21 * 4];
    if (lane == 0) {
        #pragma unroll
        for (int v = 0; v < 21; ++v) smem[v * 4 + wave] = vals[v];
    }
    __syncthreads();

    if (threadIdx.x < 21) {
        const int v = threadIdx.x;
        const float x = smem[v * 4 + 0] + smem[v * 4 + 1] +
                        smem[v * 4 + 2] + smem[v * 4 + 3];
        float* dst;
        if      (v < 4)  dst = &fsum[b * K_ + v];
        else if (v < 8)  dst = &inter[b * K_ + (v - 4)];
        else if (v < 12) dst = &psum[b * K_ + (v - 8)];
        else if (v < 16) dst = &i2s[b * K_ + (v - 12)];
        else if (v < 20) dst = &msum[b * K_ + (v - 16)];
        else             dst = &tsum[b];
        atomicAdd(dst, x);
    }
}

__global__ __launch_bounds__(128) void finalize_kernel(
    const float* __restrict__ pred_ious,    // B*K
    const float* __restrict__ fsum,
    const float* __restrict__ inter,
    const float* __restrict__ psum,
    const float* __restrict__ i2s,
    const float* __restrict__ msum,
    const float* __restrict__ tsum,
    float* __restrict__ out)                // [focal, dice, iou]
{
    const float lo[K_] = {0.00f, 0.01f, 0.09f, 0.25f};
    const float hi[K_] = {0.04f, 0.16f, 0.49f, 1.00f};
    const float SMOOTH = 0.0001f;

    const int b = threadIdx.x;              // 128 threads, one per sample
    const float ts = tsum[b];
    const float ratio = ts * (1.0f / (float)HW_);

    float cnt = 0.f, fA = 0.f, dA = 0.f, iA = 0.f;
    #pragma unroll
    for (int k = 0; k < K_; ++k) {
        const bool valid = (ratio > lo[k]) && (ratio < hi[k]);
        if (valid) {
            cnt += 1.0f;
            fA += fsum[b * K_ + k] * (1.0f / (float)HW_);
            const float in_ = inter[b * K_ + k];
            const float ps_ = psum[b * K_ + k];
            dA += 1.0f - (2.0f * in_ + SMOOTH) / (ps_ + ts + SMOOTH);
            const float i2_ = i2s[b * K_ + k];
            const float ms_ = msum[b * K_ + k];
            const float gt  = (i2_ + SMOOTH) / (ms_ + ts - i2_ + SMOOTH);
            const float d   = pred_ious[b * K_ + k] - gt;
            iA += d * d;
        }
    }
    const float invc = (cnt > 0.f) ? (1.0f / cnt) : 0.0f;
    fA *= invc; dA *= invc; iA *= invc;      // per_sample (0 when cnt==0)
    float vb = (cnt > 0.f) ? 1.0f : 0.0f;

    // Reduce 4 quantities across 128 threads (2 waves).
    float vals[4] = {fA, dA, iA, vb};
    const int lane = threadIdx.x & 63;
    const int wave = threadIdx.x >> 6;
    #pragma unroll
    for (int v = 0; v < 4; ++v) {
        float x = vals[v];
        #pragma unroll
        for (int off = 32; off > 0; off >>= 1) x += __shfl_down(x, off, 64);
        vals[v] = x;
    }
    __shared__ float smem[4 * 2];
    if (lane == 0) {
        #pragma unroll
        for (int v = 0; v < 4; ++v) smem[v * 2 + wave] = vals[v];
    }
    __syncthreads();
    if (threadIdx.x == 0) {
        const float fT  = smem[0] + smem[1];
        const float dT  = smem[2] + smem[3];
        const float iT  = smem[4] + smem[5];
        const float vbT = smem[6] + smem[7];
        const float scale = (vbT > 0.f) ? (1.0f / vbT) : 1.0f;
        out[0] = 20.0f * fT * scale;   // FOCAL_W
        out[1] = dT * scale;           // DICE_W
        out[2] = iT * scale;           // IOU_W
    }
}

extern "C" void kernel_launch(void* const* d_in, const int* in_sizes, int n_in,
                              void* d_out, int out_size, void* d_ws, size_t ws_size,
                              hipStream_t stream) {
    const float* pred_masks = (const float*)d_in[0];   // B*K*HW
    const float* pred_ious  = (const float*)d_in[1];   // B*K
    const float* targets    = (const float*)d_in[2];   // B*HW
    float* out = (float*)d_out;

    float* ws    = (float*)d_ws;
    float* fsum  = ws;            // B*K = 512
    float* inter = ws + 512;
    float* psum  = ws + 1024;
    float* i2s   = ws + 1536;
    float* msum  = ws + 2048;
    float* tsum  = ws + 2560;     // B = 128  -> total 2688 floats

    hipMemsetAsync(d_ws, 0, 2688 * sizeof(float), stream);

    partial_kernel<<<B_ * NCHUNK, BLOCK, 0, stream>>>(
        pred_masks, targets, fsum, inter, psum, i2s, msum, tsum);
    finalize_kernel<<<1, 128, 0, stream>>>(
        pred_ious, fsum, inter, psum, i2s, msum, tsum, out);
}

// Round 2
// 226.521 us; speedup vs baseline: 1.2280x; 1.2280x over previous
//
#include <hip/hip_runtime.h>
#include <math.h>

// Problem constants
#define B_   128
#define K_   4
#define HW_  65536              // 256*256

constexpr int BLOCK  = 256;
constexpr int CHUNK  = 4096;            // floats of HW per block
constexpr int NCHUNK = HW_ / CHUNK;     // 16 chunks per b
constexpr int V4_PER_THREAD = CHUNK / 4 / BLOCK; // 4 float4 per thread per tensor

// Per-element math, minimized for gfx950 VALU throughput.
// t is EXACTLY 0.0 or 1.0 (targets are a boolean cast), so:
//   pt  = t*s + (1-t)*(1-s)  == fma(t, 1-2s, s)
//   bce = -ln(pt)            (BCE is -log of true-class prob; replaces log1pf)
//   exp(-bce) == pt          (no second exp needed)
// __expf / __logf -> v_exp_f32 / v_log_f32 (native, quarter-rate);
// __builtin_amdgcn_rcpf -> v_rcp_f32 (replaces the exact-div sequence).
// Tolerance is 0.11 (bf16-level); native-precision error ~1e-6 rel.
__device__ __forceinline__ void proc_elem(float x, float t,
                                          float& fs, float& in, float& ps,
                                          float& i2, float& ms) {
    float e   = __expf(-fabsf(x));                 // e^{-|x|}
    float inv = __builtin_amdgcn_rcpf(1.0f + e);   // sigmoid(|x|)
    bool  pos = (x >= 0.0f);
    float s   = pos ? inv : 1.0f - inv;            // sigmoid(x)
    float nms = fmaf(-2.0f, s, 1.0f);              // 1 - 2s
    float pt  = fmaf(t, nms, s);                   // prob of true class
    float l   = __logf(pt);                        // ln(pt) = -bce
    float om  = 1.0f - pt;
    fs = fmaf(om * om * l, -0.8f, fs);             // += ALPHA*(1-pt)^2*bce
    float pc  = fminf(fmaxf(s, 1e-4f), 0.9999f);   // clip(sigmoid)
    ps += pc;
    in  = fmaf(pc, t, in);
    float m = pos ? 1.0f : 0.0f;                   // mask (x >= 0)
    ms += m;
    i2  = fmaf(m, t, i2);
}

__global__ __launch_bounds__(BLOCK) void partial_kernel(
    const float* __restrict__ pred_masks,   // B*K*HW
    const float* __restrict__ targets,      // B*HW
    float* __restrict__ fsum,               // B*K
    float* __restrict__ inter,              // B*K
    float* __restrict__ psum,               // B*K
    float* __restrict__ i2s,                // B*K
    float* __restrict__ msum,               // B*K
    float* __restrict__ tsum)               // B
{
    const int blk  = blockIdx.x;
    const int b    = blk / NCHUNK;
    const int c    = blk % NCHUNK;
    const int base = c * CHUNK;

    const float4* __restrict__ t4 =
        reinterpret_cast<const float4*>(targets + (size_t)b * HW_ + base);
    const float* __restrict__ xbase = pred_masks + (size_t)b * K_ * HW_ + base;

    float fs[K_] = {0.f, 0.f, 0.f, 0.f};
    float in[K_] = {0.f, 0.f, 0.f, 0.f};
    float ps[K_] = {0.f, 0.f, 0.f, 0.f};
    float i2[K_] = {0.f, 0.f, 0.f, 0.f};
    float ms[K_] = {0.f, 0.f, 0.f, 0.f};
    float ts = 0.f;

    #pragma unroll
    for (int i = 0; i < V4_PER_THREAD; ++i) {
        const int idx = threadIdx.x + i * BLOCK;   // float4 index within chunk
        const float4 tv = t4[idx];
        ts += tv.x + tv.y + tv.z + tv.w;
        #pragma unroll
        for (int k = 0; k < K_; ++k) {
            const float4 xv =
                reinterpret_cast<const float4*>(xbase + (size_t)k * HW_)[idx];
            proc_elem(xv.x, tv.x, fs[k], in[k], ps[k], i2[k], ms[k]);
            proc_elem(xv.y, tv.y, fs[k], in[k], ps[k], i2[k], ms[k]);
            proc_elem(xv.z, tv.z, fs[k], in[k], ps[k], i2[k], ms[k]);
            proc_elem(xv.w, tv.w, fs[k], in[k], ps[k], i2[k], ms[k]);
        }
    }

    // Pack 21 partials, wave-shuffle reduce (wave = 64), combine 4 waves via LDS.
    float vals[21];
    #pragma unroll
    for (int k = 0; k < K_; ++k) {
        vals[k]      = fs[k];
        vals[4 + k]  = in[k];
        vals[8 + k]  = ps[k];
        vals[12 + k] = i2[k];
        vals[16 + k] = ms[k];
    }
    vals[20] = ts;

    const int lane = threadIdx.x & 63;
    const int wave = threadIdx.x >> 6;

    #pragma unroll
    for (int v = 0; v < 21; ++v) {
        float x = vals[v];
        #pragma unroll
        for (int off = 32; off > 0; off >>= 1) x += __shfl_down(x, off, 64);
        vals[v] = x;
    }

    __shared__ float smem[21 * 4];
    if (lane == 0) {
        #pragma unroll
        for (int v = 0; v < 21; ++v) smem[v * 4 + wave] = vals[v];
    }
    __syncthreads();

    if (threadIdx.x < 21) {
        const int v = threadIdx.x;
        const float x = smem[v * 4 + 0] + smem[v * 4 + 1] +
                        smem[v * 4 + 2] + smem[v * 4 + 3];
        float* dst;
        if      (v < 4)  dst = &fsum[b * K_ + v];
        else if (v < 8)  dst = &inter[b * K_ + (v - 4)];
        else if (v < 12) dst = &psum[b * K_ + (v - 8)];
        else if (v < 16) dst = &i2s[b * K_ + (v - 12)];
        else if (v < 20) dst = &msum[b * K_ + (v - 16)];
        else             dst = &tsum[b];
        atomicAdd(dst, x);
    }
}

__global__ __launch_bounds__(128) void finalize_kernel(
    const float* __restrict__ pred_ious,    // B*K
    const float* __restrict__ fsum,
    const float* __restrict__ inter,
    const float* __restrict__ psum,
    const float* __restrict__ i2s,
    const float* __restrict__ msum,
    const float* __restrict__ tsum,
    float* __restrict__ out)                // [focal, dice, iou]
{
    const float lo[K_] = {0.00f, 0.01f, 0.09f, 0.25f};
    const float hi[K_] = {0.04f, 0.16f, 0.49f, 1.00f};
    const float SMOOTH = 0.0001f;

    const int b = threadIdx.x;              // 128 threads, one per sample
    const float ts = tsum[b];
    const float ratio = ts * (1.0f / (float)HW_);

    float cnt = 0.f, fA = 0.f, dA = 0.f, iA = 0.f;
    #pragma unroll
    for (int k = 0; k < K_; ++k) {
        const bool valid = (ratio > lo[k]) && (ratio < hi[k]);
        if (valid) {
            cnt += 1.0f;
            fA += fsum[b * K_ + k] * (1.0f / (float)HW_);
            const float in_ = inter[b * K_ + k];
            const float ps_ = psum[b * K_ + k];
            dA += 1.0f - (2.0f * in_ + SMOOTH) / (ps_ + ts + SMOOTH);
            const float i2_ = i2s[b * K_ + k];
            const float ms_ = msum[b * K_ + k];
            const float gt  = (i2_ + SMOOTH) / (ms_ + ts - i2_ + SMOOTH);
            const float d   = pred_ious[b * K_ + k] - gt;
            iA += d * d;
        }
    }
    const float invc = (cnt > 0.f) ? (1.0f / cnt) : 0.0f;
    fA *= invc; dA *= invc; iA *= invc;      // per_sample (0 when cnt==0)
    float vb = (cnt > 0.f) ? 1.0f : 0.0f;

    // Reduce 4 quantities across 128 threads (2 waves).
    float vals[4] = {fA, dA, iA, vb};
    const int lane = threadIdx.x & 63;
    const int wave = threadIdx.x >> 6;
    #pragma unroll
    for (int v = 0; v < 4; ++v) {
        float x = vals[v];
        #pragma unroll
        for (int off = 32; off > 0; off >>= 1) x += __shfl_down(x, off, 64);
        vals[v] = x;
    }
    __shared__ float smem[4 * 2];
    if (lane == 0) {
        #pragma unroll
        for (int v = 0; v < 4; ++v) smem[v * 2 + wave] = vals[v];
    }
    __syncthreads();
    if (threadIdx.x == 0) {
        const float fT  = smem[0] + smem[1];
        const float dT  = smem[2] + smem[3];
        const float iT  = smem[4] + smem[5];
        const float vbT = smem[6] + smem[7];
        const float scale = (vbT > 0.f) ? (1.0f / vbT) : 1.0f;
        out[0] = 20.0f * fT * scale;   // FOCAL_W
        out[1] = dT * scale;           // DICE_W
        out[2] = iT * scale;           // IOU_W
    }
}

extern "C" void kernel_launch(void* const* d_in, const int* in_sizes, int n_in,
                              void* d_out, int out_size, void* d_ws, size_t ws_size,
                              hipStream_t stream) {
    const float* pred_masks = (const float*)d_in[0];   // B*K*HW
    const float* pred_ious  = (const float*)d_in[1];   // B*K
    const float* targets    = (const float*)d_in[2];   // B*HW
    float* out = (float*)d_out;

    float* ws    = (float*)d_ws;
    float* fsum  = ws;            // B*K = 512
    float* inter = ws + 512;
    float* psum  = ws + 1024;
    float* i2s   = ws + 1536;
    float* msum  = ws + 2048;
    float* tsum  = ws + 2560;     // B = 128  -> total 2688 floats

    hipMemsetAsync(d_ws, 0, 2688 * sizeof(float), stream);

    partial_kernel<<<B_ * NCHUNK, BLOCK, 0, stream>>>(
        pred_masks, targets, fsum, inter, psum, i2s, msum, tsum);
    finalize_kernel<<<1, 128, 0, stream>>>(
        pred_ious, fsum, inter, psum, i2s, msum, tsum, out);
}

// Round 3
// 221.341 us; speedup vs baseline: 1.2568x; 1.0234x over previous
//
#include <hip/hip_runtime.h>
#include <math.h>

// Problem constants
#define B_   128
#define K_   4
#define HW_  65536              // 256*256

constexpr int BLOCK = 256;
constexpr int NC    = 8;                    // chunks per (b,k) plane
constexpr int CHUNK = HW_ / NC;             // 8192 floats
constexpr int V4    = CHUNK / 4 / BLOCK;    // 8 float4 per thread per tensor

// Per-element math (t is exactly 0.0 or 1.0):
//   s   = sigmoid(x)
//   pt  = t*s + (1-t)*(1-s) = fma(t, 1-2s, s)   (true-class probability)
//   bce = -ln(pt); exp(-bce) == pt
//   focal += ALPHA * (1-pt)^2 * bce
// Native v_exp/v_rcp/v_log (quarter-rate) — rel err ~1e-6, threshold is 0.11.
__device__ __forceinline__ void proc_elem(float x, float t,
                                          float& fs, float& in, float& ps,
                                          float& i2, float& ms) {
    float e   = __expf(-fabsf(x));                 // e^{-|x|}
    float inv = __builtin_amdgcn_rcpf(1.0f + e);   // sigmoid(|x|)
    bool  pos = (x >= 0.0f);
    float s   = pos ? inv : 1.0f - inv;            // sigmoid(x)
    float nms = fmaf(-2.0f, s, 1.0f);              // 1 - 2s
    float pt  = fmaf(t, nms, s);                   // prob of true class
    float l   = __logf(pt);                        // ln(pt) = -bce
    float om  = 1.0f - pt;
    fs = fmaf(om * om * l, -0.8f, fs);             // += ALPHA*(1-pt)^2*bce
    float pc  = fminf(fmaxf(s, 1e-4f), 0.9999f);   // clip(sigmoid) -> v_med3
    ps += pc;
    in  = fmaf(pc, t, in);
    float m = pos ? 1.0f : 0.0f;                   // mask (x >= 0)
    ms += m;
    i2  = fmaf(m, t, i2);
}

// One block per (b, chunk, k): only 6 live accumulators per thread, so the
// 64-VGPR budget (launch_bounds 256,8 -> 32 waves/CU) leaves room for the
// compiler to keep many float4 loads in flight. k is the fastest-varying
// grid index so the 4 blocks sharing a target chunk run concurrently (L3).
__global__ __launch_bounds__(BLOCK, 8) void partial_kernel(
    const float* __restrict__ pred_masks,   // B*K*HW
    const float* __restrict__ targets,      // B*HW
    float* __restrict__ fsum,               // B*K
    float* __restrict__ inter,              // B*K
    float* __restrict__ psum,               // B*K
    float* __restrict__ i2s,                // B*K
    float* __restrict__ msum,               // B*K
    float* __restrict__ tsum)               // B  (accumulated K_ times)
{
    const int blk = blockIdx.x;             // ((b*NC + c)*K_ + k)
    const int k   = blk & (K_ - 1);
    const int bc  = blk >> 2;
    const int c   = bc & (NC - 1);
    const int b   = bc >> 3;

    const float4* __restrict__ t4 =
        reinterpret_cast<const float4*>(targets + (size_t)b * HW_ + c * CHUNK);
    const float4* __restrict__ x4 =
        reinterpret_cast<const float4*>(pred_masks +
            ((size_t)(b * K_ + k)) * HW_ + c * CHUNK);

    float fs = 0.f, in = 0.f, ps = 0.f, i2 = 0.f, ms = 0.f, ts = 0.f;

    #pragma unroll
    for (int i = 0; i < V4; ++i) {
        const int idx = threadIdx.x + i * BLOCK;
        const float4 tv = t4[idx];
        const float4 xv = x4[idx];
        proc_elem(xv.x, tv.x, fs, in, ps, i2, ms);
        proc_elem(xv.y, tv.y, fs, in, ps, i2, ms);
        proc_elem(xv.z, tv.z, fs, in, ps, i2, ms);
        proc_elem(xv.w, tv.w, fs, in, ps, i2, ms);
        ts += tv.x + tv.y + tv.z + tv.w;
    }

    // Reduce 6 partials: wave shuffle (64 lanes) -> LDS across 4 waves -> atomic.
    float vals[6] = {fs, in, ps, i2, ms, ts};
    const int lane = threadIdx.x & 63;
    const int wave = threadIdx.x >> 6;

    #pragma unroll
    for (int v = 0; v < 6; ++v) {
        float x = vals[v];
        #pragma unroll
        for (int off = 32; off > 0; off >>= 1) x += __shfl_down(x, off, 64);
        vals[v] = x;
    }

    __shared__ float smem[6 * 4];
    if (lane == 0) {
        #pragma unroll
        for (int v = 0; v < 6; ++v) smem[v * 4 + wave] = vals[v];
    }
    __syncthreads();

    if (threadIdx.x < 6) {
        const int v = threadIdx.x;
        const float x = smem[v * 4 + 0] + smem[v * 4 + 1] +
                        smem[v * 4 + 2] + smem[v * 4 + 3];
        const int bk = b * K_ + k;
        float* dst;
        if      (v == 0) dst = &fsum[bk];
        else if (v == 1) dst = &inter[bk];
        else if (v == 2) dst = &psum[bk];
        else if (v == 3) dst = &i2s[bk];
        else if (v == 4) dst = &msum[bk];
        else             dst = &tsum[b];    // summed by all K_ k-blocks
        atomicAdd(dst, x);
    }
}

__global__ __launch_bounds__(128) void finalize_kernel(
    const float* __restrict__ pred_ious,    // B*K
    const float* __restrict__ fsum,
    const float* __restrict__ inter,
    const float* __restrict__ psum,
    const float* __restrict__ i2s,
    const float* __restrict__ msum,
    const float* __restrict__ tsum,
    float* __restrict__ out)                // [focal, dice, iou]
{
    const float lo[K_] = {0.00f, 0.01f, 0.09f, 0.25f};
    const float hi[K_] = {0.04f, 0.16f, 0.49f, 1.00f};
    const float SMOOTH = 0.0001f;

    const int b = threadIdx.x;              // 128 threads, one per sample
    const float ts = tsum[b] * 0.25f;       // undo K_-fold accumulation
    const float ratio = ts * (1.0f / (float)HW_);

    float cnt = 0.f, fA = 0.f, dA = 0.f, iA = 0.f;
    #pragma unroll
    for (int k = 0; k < K_; ++k) {
        const bool valid = (ratio > lo[k]) && (ratio < hi[k]);
        if (valid) {
            cnt += 1.0f;
            fA += fsum[b * K_ + k] * (1.0f / (float)HW_);
            const float in_ = inter[b * K_ + k];
            const float ps_ = psum[b * K_ + k];
            dA += 1.0f - (2.0f * in_ + SMOOTH) / (ps_ + ts + SMOOTH);
            const float i2_ = i2s[b * K_ + k];
            const float ms_ = msum[b * K_ + k];
            const float gt  = (i2_ + SMOOTH) / (ms_ + ts - i2_ + SMOOTH);
            const float d   = pred_ious[b * K_ + k] - gt;
            iA += d * d;
        }
    }
    const float invc = (cnt > 0.f) ? (1.0f / cnt) : 0.0f;
    fA *= invc; dA *= invc; iA *= invc;      // per_sample (0 when cnt==0)
    float vb = (cnt > 0.f) ? 1.0f : 0.0f;

    // Reduce 4 quantities across 128 threads (2 waves).
    float vals[4] = {fA, dA, iA, vb};
    const int lane = threadIdx.x & 63;
    const int wave = threadIdx.x >> 6;
    #pragma unroll
    for (int v = 0; v < 4; ++v) {
        float x = vals[v];
        #pragma unroll
        for (int off = 32; off > 0; off >>= 1) x += __shfl_down(x, off, 64);
        vals[v] = x;
    }
    __shared__ float smem[4 * 2];
    if (lane == 0) {
        #pragma unroll
        for (int v = 0; v < 4; ++v) smem[v * 2 + wave] = vals[v];
    }
    __syncthreads();
    if (threadIdx.x == 0) {
        const float fT  = smem[0] + smem[1];
        const float dT  = smem[2] + smem[3];
        const float iT  = smem[4] + smem[5];
        const float vbT = smem[6] + smem[7];
        const float scale = (vbT > 0.f) ? (1.0f / vbT) : 1.0f;
        out[0] = 20.0f * fT * scale;   // FOCAL_W
        out[1] = dT * scale;           // DICE_W
        out[2] = iT * scale;           // IOU_W
    }
}

extern "C" void kernel_launch(void* const* d_in, const int* in_sizes, int n_in,
                              void* d_out, int out_size, void* d_ws, size_t ws_size,
                              hipStream_t stream) {
    const float* pred_masks = (const float*)d_in[0];   // B*K*HW
    const float* pred_ious  = (const float*)d_in[1];   // B*K
    const float* targets    = (const float*)d_in[2];   // B*HW
    float* out = (float*)d_out;

    float* ws    = (float*)d_ws;
    float* fsum  = ws;            // B*K = 512
    float* inter = ws + 512;
    float* psum  = ws + 1024;
    float* i2s   = ws + 1536;
    float* msum  = ws + 2048;
    float* tsum  = ws + 2560;     // B = 128  -> total 2688 floats

    hipMemsetAsync(d_ws, 0, 2688 * sizeof(float), stream);

    partial_kernel<<<B_ * NC * K_, BLOCK, 0, stream>>>(
        pred_masks, targets, fsum, inter, psum, i2s, msum, tsum);
    finalize_kernel<<<1, 128, 0, stream>>>(
        pred_ious, fsum, inter, psum, i2s, msum, tsum, out);
}

// Round 5
// 214.784 us; speedup vs baseline: 1.2951x; 1.0305x over previous
//
#include <hip/hip_runtime.h>
#include <math.h>

// Problem constants
#define B_   128
#define K_   4
#define HW_  65536              // 256*256

constexpr int BLOCK = 256;
constexpr int NC    = 16;                   // chunks per b
constexpr int CHUNK = HW_ / NC;             // 4096 floats
constexpr int G     = CHUNK / 4 / BLOCK;    // 4 pipeline groups (1 float4/tensor each)

// Native clang vector type: __builtin_nontemporal_load requires a real
// vector (HIP's float4 is a struct and is rejected).
typedef float vfloat4 __attribute__((ext_vector_type(4)));

// Per-element math (t is exactly 0.0 or 1.0):
//   s   = sigmoid(x)
//   pt  = t*s + (1-t)*(1-s) = fma(t, 1-2s, s)   (true-class probability)
//   bce = -ln(pt); exp(-bce) == pt
//   focal += ALPHA * (1-pt)^2 * bce
// Native v_exp/v_rcp/v_log (quarter-rate) — rel err ~1e-6, threshold is 0.11.
__device__ __forceinline__ void proc_elem(float x, float t,
                                          float& fs, float& in, float& ps,
                                          float& i2, float& ms) {
    float e   = __expf(-fabsf(x));                 // e^{-|x|} (neg+abs are free mods)
    float inv = __builtin_amdgcn_rcpf(1.0f + e);   // sigmoid(|x|)
    bool  pos = (x >= 0.0f);
    float s   = pos ? inv : 1.0f - inv;            // sigmoid(x)
    float nms = fmaf(-2.0f, s, 1.0f);              // 1 - 2s
    float pt  = fmaf(t, nms, s);                   // prob of true class
    float l   = __logf(pt);                        // ln(pt) = -bce
    float om  = 1.0f - pt;
    fs = fmaf(om * om * l, -0.8f, fs);             // += ALPHA*(1-pt)^2*bce
    float pc  = fminf(fmaxf(s, 1e-4f), 0.9999f);   // clip(sigmoid) -> v_med3
    ps += pc;
    in  = fmaf(pc, t, in);
    float m = pos ? 1.0f : 0.0f;                   // mask (x >= 0)
    ms += m;
    i2  = fmaf(m, t, i2);
}

__device__ __forceinline__ void proc4(const vfloat4& xv, const vfloat4& tv,
                                      float& fs, float& in, float& ps,
                                      float& i2, float& ms) {
    proc_elem(xv.x, tv.x, fs, in, ps, i2, ms);
    proc_elem(xv.y, tv.y, fs, in, ps, i2, ms);
    proc_elem(xv.z, tv.z, fs, in, ps, i2, ms);
    proc_elem(xv.w, tv.w, fs, in, ps, i2, ms);
}

// Fused-K: one block per (b, chunk). Every input byte is read exactly once
// chip-wide (no L3-reuse dependence — the harness's 512 MB ws-poison evicts
// L3 every iteration anyway). launch_bounds(256,4) caps VGPR at 128: room
// for 21 accumulators + a 1-deep software pipeline of 5 nontemporal float4
// loads, keeping >=5 KB per wave in flight (Little's law for 6.3 TB/s needs
// only ~9 KB per CU).
__global__ __launch_bounds__(BLOCK, 4) void partial_kernel(
    const float* __restrict__ pred_masks,   // B*K*HW
    const float* __restrict__ targets,      // B*HW
    float* __restrict__ fsum,               // B*K
    float* __restrict__ inter,              // B*K
    float* __restrict__ psum,               // B*K
    float* __restrict__ i2s,                // B*K
    float* __restrict__ msum,               // B*K
    float* __restrict__ tsum)               // B
{
    const int blk = blockIdx.x;
    const int c   = blk & (NC - 1);
    const int b   = blk >> 4;               // NC == 16

    const vfloat4* __restrict__ t4 =
        reinterpret_cast<const vfloat4*>(targets + (size_t)b * HW_ + c * CHUNK);
    const float*  xb = pred_masks + (size_t)b * K_ * HW_ + c * CHUNK;
    const vfloat4* __restrict__ x0 = reinterpret_cast<const vfloat4*>(xb);
    const vfloat4* __restrict__ x1 = reinterpret_cast<const vfloat4*>(xb + HW_);
    const vfloat4* __restrict__ x2 = reinterpret_cast<const vfloat4*>(xb + 2 * HW_);
    const vfloat4* __restrict__ x3 = reinterpret_cast<const vfloat4*>(xb + 3 * HW_);

    float fs[K_] = {0.f, 0.f, 0.f, 0.f};
    float in[K_] = {0.f, 0.f, 0.f, 0.f};
    float ps[K_] = {0.f, 0.f, 0.f, 0.f};
    float i2[K_] = {0.f, 0.f, 0.f, 0.f};
    float ms[K_] = {0.f, 0.f, 0.f, 0.f};
    float ts = 0.f;

    int idx = threadIdx.x;
    vfloat4 tv  = __builtin_nontemporal_load(&t4[idx]);
    vfloat4 xv0 = __builtin_nontemporal_load(&x0[idx]);
    vfloat4 xv1 = __builtin_nontemporal_load(&x1[idx]);
    vfloat4 xv2 = __builtin_nontemporal_load(&x2[idx]);
    vfloat4 xv3 = __builtin_nontemporal_load(&x3[idx]);

    #pragma unroll
    for (int g = 0; g < G; ++g) {
        vfloat4 ntv, nx0, nx1, nx2, nx3;
        if (g < G - 1) {                    // compile-time resolved (unrolled)
            const int nidx = idx + BLOCK;
            ntv = __builtin_nontemporal_load(&t4[nidx]);
            nx0 = __builtin_nontemporal_load(&x0[nidx]);
            nx1 = __builtin_nontemporal_load(&x1[nidx]);
            nx2 = __builtin_nontemporal_load(&x2[nidx]);
            nx3 = __builtin_nontemporal_load(&x3[nidx]);
        }
        proc4(xv0, tv, fs[0], in[0], ps[0], i2[0], ms[0]);
        proc4(xv1, tv, fs[1], in[1], ps[1], i2[1], ms[1]);
        proc4(xv2, tv, fs[2], in[2], ps[2], i2[2], ms[2]);
        proc4(xv3, tv, fs[3], in[3], ps[3], i2[3], ms[3]);
        ts += tv.x + tv.y + tv.z + tv.w;
        if (g < G - 1) {
            idx += BLOCK;
            tv = ntv; xv0 = nx0; xv1 = nx1; xv2 = nx2; xv3 = nx3;
        }
    }

    // Pack 21 partials, wave-shuffle reduce (wave = 64), combine 4 waves via LDS.
    float vals[21];
    #pragma unroll
    for (int k = 0; k < K_; ++k) {
        vals[k]      = fs[k];
        vals[4 + k]  = in[k];
        vals[8 + k]  = ps[k];
        vals[12 + k] = i2[k];
        vals[16 + k] = ms[k];
    }
    vals[20] = ts;

    const int lane = threadIdx.x & 63;
    const int wave = threadIdx.x >> 6;

    #pragma unroll
    for (int v = 0; v < 21; ++v) {
        float x = vals[v];
        #pragma unroll
        for (int off = 32; off > 0; off >>= 1) x += __shfl_down(x, off, 64);
        vals[v] = x;
    }

    __shared__ float smem[21 * 4];
    if (lane == 0) {
        #pragma unroll
        for (int v = 0; v < 21; ++v) smem[v * 4 + wave] = vals[v];
    }
    __syncthreads();

    if (threadIdx.x < 21) {
        const int v = threadIdx.x;
        const float x = smem[v * 4 + 0] + smem[v * 4 + 1] +
                        smem[v * 4 + 2] + smem[v * 4 + 3];
        float* dst;
        if      (v < 4)  dst = &fsum[b * K_ + v];
        else if (v < 8)  dst = &inter[b * K_ + (v - 4)];
        else if (v < 12) dst = &psum[b * K_ + (v - 8)];
        else if (v < 16) dst = &i2s[b * K_ + (v - 12)];
        else if (v < 20) dst = &msum[b * K_ + (v - 16)];
        else             dst = &tsum[b];
        atomicAdd(dst, x);
    }
}

__global__ __launch_bounds__(128) void finalize_kernel(
    const float* __restrict__ pred_ious,    // B*K
    const float* __restrict__ fsum,
    const float* __restrict__ inter,
    const float* __restrict__ psum,
    const float* __restrict__ i2s,
    const float* __restrict__ msum,
    const float* __restrict__ tsum,
    float* __restrict__ out)                // [focal, dice, iou]
{
    const float lo[K_] = {0.00f, 0.01f, 0.09f, 0.25f};
    const float hi[K_] = {0.04f, 0.16f, 0.49f, 1.00f};
    const float SMOOTH = 0.0001f;

    const int b = threadIdx.x;              // 128 threads, one per sample
    const float ts = tsum[b];
    const float ratio = ts * (1.0f / (float)HW_);

    float cnt = 0.f, fA = 0.f, dA = 0.f, iA = 0.f;
    #pragma unroll
    for (int k = 0; k < K_; ++k) {
        const bool valid = (ratio > lo[k]) && (ratio < hi[k]);
        if (valid) {
            cnt += 1.0f;
            fA += fsum[b * K_ + k] * (1.0f / (float)HW_);
            const float in_ = inter[b * K_ + k];
            const float ps_ = psum[b * K_ + k];
            dA += 1.0f - (2.0f * in_ + SMOOTH) / (ps_ + ts + SMOOTH);
            const float i2_ = i2s[b * K_ + k];
            const float ms_ = msum[b * K_ + k];
            const float gt  = (i2_ + SMOOTH) / (ms_ + ts - i2_ + SMOOTH);
            const float d   = pred_ious[b * K_ + k] - gt;
            iA += d * d;
        }
    }
    const float invc = (cnt > 0.f) ? (1.0f / cnt) : 0.0f;
    fA *= invc; dA *= invc; iA *= invc;      // per_sample (0 when cnt==0)
    float vb = (cnt > 0.f) ? 1.0f : 0.0f;

    // Reduce 4 quantities across 128 threads (2 waves).
    float vals[4] = {fA, dA, iA, vb};
    const int lane = threadIdx.x & 63;
    const int wave = threadIdx.x >> 6;
    #pragma unroll
    for (int v = 0; v < 4; ++v) {
        float x = vals[v];
        #pragma unroll
        for (int off = 32; off > 0; off >>= 1) x += __shfl_down(x, off, 64);
        vals[v] = x;
    }
    __shared__ float smem[4 * 2];
    if (lane == 0) {
        #pragma unroll
        for (int v = 0; v < 4; ++v) smem[v * 2 + wave] = vals[v];
    }
    __syncthreads();
    if (threadIdx.x == 0) {
        const float fT  = smem[0] + smem[1];
        const float dT  = smem[2] + smem[3];
        const float iT  = smem[4] + smem[5];
        const float vbT = smem[6] + smem[7];
        const float scale = (vbT > 0.f) ? (1.0f / vbT) : 1.0f;
        out[0] = 20.0f * fT * scale;   // FOCAL_W
        out[1] = dT * scale;           // DICE_W
        out[2] = iT * scale;           // IOU_W
    }
}

extern "C" void kernel_launch(void* const* d_in, const int* in_sizes, int n_in,
                              void* d_out, int out_size, void* d_ws, size_t ws_size,
                              hipStream_t stream) {
    const float* pred_masks = (const float*)d_in[0];   // B*K*HW
    const float* pred_ious  = (const float*)d_in[1];   // B*K
    const float* targets    = (const float*)d_in[2];   // B*HW
    float* out = (float*)d_out;

    float* ws    = (float*)d_ws;
    float* fsum  = ws;            // B*K = 512
    float* inter = ws + 512;
    float* psum  = ws + 1024;
    float* i2s   = ws + 1536;
    float* msum  = ws + 2048;
    float* tsum  = ws + 2560;     // B = 128  -> total 2688 floats

    (void)hipMemsetAsync(d_ws, 0, 2688 * sizeof(float), stream);

    partial_kernel<<<B_ * NC, BLOCK, 0, stream>>>(
        pred_masks, targets, fsum, inter, psum, i2s, msum, tsum);
    finalize_kernel<<<1, 128, 0, stream>>>(
        pred_ious, fsum, inter, psum, i2s, msum, tsum, out);
}